// Round 14
// baseline (438.742 us; speedup 1.0000x reference)
//
#include <hip/hip_runtime.h>
#include <math.h>

// ---- problem constants ----
#define NFINE   80000
#define NCRS    2048
#define NSRC    1024
#define NNB     30
#define KP      15
#define C1D     128
#define C2D     256
#define GD      256
#define DGK     10
#define FINALD  32
#define DECOUT  34

#define NCHUNK  8      // attention key-split
#define CHUNK   128    // 1024 / NCHUNK
#define TK      16     // attention LDS key tile (register-scored)
#define KC      4      // hh-gemm K chunks
#define KSTEP   480    // 1920 / KC
#define GTR     16     // hh-gemm rows per block
#define FINEB   10000  // kpconv_fine blocks (8 points each)

// =====================================================================
// fused kpconv_fine (blocks 0..9999) + knn (blocks 10000..12047)
// =====================================================================
__global__ __launch_bounds__(256) void fine_knn(
    const float* __restrict__ pts, const float* __restrict__ feat,
    const int* __restrict__ nbr, const float* __restrict__ kp,
    const float* __restrict__ W, float* __restrict__ out,
    const float* __restrict__ pc, int* __restrict__ knn)
{
    __shared__ float contrib[8][NNB][17];
    __shared__ float h[8][KP + 1];
    __shared__ float d2s[NSRC];
    __shared__ float wval[4];
    __shared__ int   widx[4];
    int t = threadIdx.x;
    if (blockIdx.x < FINEB) {
        int w = t >> 6, lane = t & 63;
        int half = lane >> 5, hl = lane & 31;
        int pslot = w*2 + half;
        int n = blockIdx.x * 8 + pslot;
        float kx[KP], ky[KP], kz[KP], kk[KP];
#pragma unroll
        for (int k = 0; k < KP; k++) {
            kx[k] = kp[k*3]; ky[k] = kp[k*3+1]; kz[k] = kp[k*3+2];
            kk[k] = kx[k]*kx[k] + ky[k]*ky[k] + kz[k]*kz[k];
        }
        if (hl < NNB) {
            float qx = pts[n*3], qy = pts[n*3+1], qz = pts[n*3+2];
            int id = nbr[n*NNB + hl];
            float rx = pts[id*3]-qx, ry = pts[id*3+1]-qy, rz = pts[id*3+2]-qz;
            float rr = rx*rx + ry*ry + rz*rz;
            float f = feat[id];
#pragma unroll
            for (int k = 0; k < KP; k++) {
                float d2 = rr + kk[k] - 2.f*(rx*kx[k] + ry*ky[k] + rz*kz[k]);
                float infl = fmaxf(1.f - sqrtf(fmaxf(d2, 1e-12f)), 0.f); // extent=1
                contrib[pslot][hl][k] = infl * f;
            }
        }
        __syncthreads();
        if (hl < KP) {
            float s = 0.f;
#pragma unroll
            for (int j = 0; j < NNB; j++) s += contrib[pslot][j][hl];
            h[pslot][hl] = s;
        }
        __syncthreads();
        int nA = blockIdx.x * 8 + w*2;
        float a0 = 0.f, a1 = 0.f, b0 = 0.f, b1 = 0.f;
#pragma unroll
        for (int k = 0; k < KP; k++) {
            float w0 = W[k*C1D + lane];
            float w1 = W[k*C1D + 64 + lane];
            float hA = h[w*2][k], hB = h[w*2+1][k];
            a0 += hA*w0; a1 += hA*w1;
            b0 += hB*w0; b1 += hB*w1;
        }
        out[(size_t)nA*C1D + lane]          = a0;
        out[(size_t)nA*C1D + 64 + lane]     = a1;
        out[(size_t)(nA+1)*C1D + lane]      = b0;
        out[(size_t)(nA+1)*C1D + 64 + lane] = b1;
    } else {
        int g = blockIdx.x - FINEB;       // query 0..2047
        int base = (g < NSRC) ? 0 : NSRC;
        int local = g - base;
        const float* P = pc + (size_t)base*3;
        float qx = P[local*3], qy = P[local*3+1], qz = P[local*3+2];
        float sqn = qx*qx + qy*qy + qz*qz;
#pragma unroll
        for (int ii = 0; ii < 4; ii++) {
            int m = t + ii*256;
            float px = P[m*3], py = P[m*3+1], pz = P[m*3+2];
            float sqm = px*px + py*py + pz*pz;
            d2s[m] = sqn + sqm - 2.f*(qx*px + qy*py + qz*pz);
        }
        __syncthreads();
        for (int r = 0; r < DGK; r++) {
            float bv = 3.4e38f; int bidx = NSRC;
#pragma unroll
            for (int ii = 0; ii < 4; ii++) {
                int m = t + ii*256;
                float v = d2s[m];
                if (v < bv) { bv = v; bidx = m; }   // ascending m: ties keep lower
            }
#pragma unroll
            for (int off = 32; off >= 1; off >>= 1) {
                float ov = __shfl_xor(bv, off);
                int   oi = __shfl_xor(bidx, off);
                if (ov < bv || (ov == bv && oi < bidx)) { bv = ov; bidx = oi; }
            }
            if ((t & 63) == 0) { wval[t >> 6] = bv; widx[t >> 6] = bidx; }
            __syncthreads();
            if (t == 0) {
                float fv = wval[0]; int fi = widx[0];
#pragma unroll
                for (int wv2 = 1; wv2 < 4; wv2++)
                    if (wval[wv2] < fv || (wval[wv2] == fv && widx[wv2] < fi)) {
                        fv = wval[wv2]; fi = widx[wv2];
                    }
                knn[g*DGK + r] = fi;
                d2s[fi] = 3.4e38f;
            }
            __syncthreads();
        }
    }
}

// =====================================================================
// hh for each coarse point -> global
// =====================================================================
__global__ __launch_bounds__(256) void hh_kernel(
    const float* __restrict__ pc, const float* __restrict__ pf,
    const float* __restrict__ xf, const int* __restrict__ pool,
    const float* __restrict__ kp, float* __restrict__ hhg)
{
    int n = blockIdx.x, t = threadIdx.x;
    __shared__ float kx[KP], ky[KP], kz[KP], kk[KP];
    __shared__ float rel[NNB][4];
    __shared__ int   ids[NNB];
    __shared__ float infl[NNB][KP + 1];
    __shared__ float nf[NNB][C1D];
    if (t < KP) {
        float a = kp[t*3], b = kp[t*3+1], c = kp[t*3+2];
        kx[t] = a; ky[t] = b; kz[t] = c; kk[t] = a*a + b*b + c*c;
    }
    if (t < NNB) {
        int id = pool[n*NNB + t]; ids[t] = id;
        float qx = pc[n*3], qy = pc[n*3+1], qz = pc[n*3+2];
        float rx = pf[id*3]-qx, ry = pf[id*3+1]-qy, rz = pf[id*3+2]-qz;
        rel[t][0] = rx; rel[t][1] = ry; rel[t][2] = rz;
        rel[t][3] = rx*rx + ry*ry + rz*rz;
    }
    __syncthreads();
    for (int i = t; i < NNB*KP; i += 256) {
        int j = i / KP, kq = i % KP;
        float d2 = rel[j][3] + kk[kq]
                 - 2.f*(rel[j][0]*kx[kq] + rel[j][1]*ky[kq] + rel[j][2]*kz[kq]);
        infl[j][kq] = fmaxf(1.f - sqrtf(fmaxf(d2, 1e-12f)) * 0.5f, 0.f); // extent=2
    }
    for (int i = t; i < NNB*C1D; i += 256) {
        int j = i >> 7, c = i & 127;
        nf[j][c] = xf[(size_t)ids[j]*C1D + c];
    }
    __syncthreads();
    for (int i = t; i < KP*C1D; i += 256) {
        int kq = i >> 7, c = i & 127;
        float s = 0.f;
#pragma unroll
        for (int j = 0; j < NNB; j++) s += infl[j][kq] * nf[j][c];
        hhg[(size_t)n*(KP*C1D) + i] = s;
    }
}

// =====================================================================
// hh GEMM split-K: block = (16 rows, 480-K chunk). partials to pbuf.
// =====================================================================
__global__ __launch_bounds__(256) void hh_gemm(
    const float* __restrict__ hhg, const float* __restrict__ W,
    float* __restrict__ pbuf)
{
    int t = threadIdx.x;
    int rg = blockIdx.x >> 2, kc = blockIdx.x & 3;
    int n0 = rg * GTR, kb0 = kc * KSTEP;
    __shared__ float xi[GTR][KSTEP];   // 30720 B, row-major
    float* xf = &xi[0][0];
    for (int i = t; i < GTR*KSTEP; i += 256) {
        int r = i / KSTEP, c = i - r*KSTEP;
        xf[i] = hhg[(size_t)(n0 + r)*(KP*C1D) + kb0 + c];
    }
    __syncthreads();
    float a[GTR];
#pragma unroll
    for (int r = 0; r < GTR; r++) a[r] = 0.f;
    for (int c = 0; c < KSTEP; c += 4) {
        float w0 = W[(size_t)(kb0+c+0)*C2D + t];
        float w1 = W[(size_t)(kb0+c+1)*C2D + t];
        float w2 = W[(size_t)(kb0+c+2)*C2D + t];
        float w3 = W[(size_t)(kb0+c+3)*C2D + t];
#pragma unroll
        for (int r = 0; r < GTR; r++) {
            float4 xv = *(const float4*)&xi[r][c];
            a[r] += xv.x*w0 + xv.y*w1 + xv.z*w2 + xv.w*w3;
        }
    }
#pragma unroll
    for (int r = 0; r < GTR; r++)
        pbuf[(size_t)kc*NCRS*C2D + (size_t)(n0+r)*C2D + t] = a[r];
}

// =====================================================================
// bottle_self1: feats_c = (sum_kc pbuf)@Wb + bb  (kept in LDS only),
// then Y1 = feats_c @ [W1|W2]. 4 rows/block, 512 blocks, 256 thr.
// =====================================================================
__global__ __launch_bounds__(256) void bottle_self1(
    const float* __restrict__ pbuf, const float* __restrict__ Wb,
    const float* __restrict__ bb, const float* __restrict__ Ws,
    float* __restrict__ Y)
{
    int t = threadIdx.x, n0 = blockIdx.x * 4;
    const size_t MN = (size_t)NCRS*C2D;
    __shared__ float xi[4][C2D];
    __shared__ float fc[4][C2D];
    for (int i = t; i < 4*C2D; i += 256) {
        int r = i >> 8, c = i & 255;
        size_t off = (size_t)(n0+r)*C2D + c;
        xi[r][c] = pbuf[off] + pbuf[MN+off] + pbuf[2*MN+off] + pbuf[3*MN+off];
    }
    __syncthreads();
    {
        float a[4] = {0.f, 0.f, 0.f, 0.f};
        for (int c = 0; c < C2D; c += 4) {
            float w0 = Wb[(c+0)*GD + t];
            float w1 = Wb[(c+1)*GD + t];
            float w2 = Wb[(c+2)*GD + t];
            float w3 = Wb[(c+3)*GD + t];
#pragma unroll
            for (int r = 0; r < 4; r++) {
                float4 xv = *(const float4*)&xi[r][c];
                a[r] += xv.x*w0 + xv.y*w1 + xv.z*w2 + xv.w*w3;
            }
        }
        float bv = bb[t];
#pragma unroll
        for (int r = 0; r < 4; r++) fc[r][t] = a[r] + bv;
    }
    __syncthreads();
    float aA[4] = {0.f,0.f,0.f,0.f}, aB[4] = {0.f,0.f,0.f,0.f};
    const float* wA = Ws + t;
    const float* wB = Ws + (size_t)GD*GD + t;
    for (int c = 0; c < GD; c += 4) {
        float wa0 = wA[(size_t)(c+0)*GD], wa1 = wA[(size_t)(c+1)*GD];
        float wa2 = wA[(size_t)(c+2)*GD], wa3 = wA[(size_t)(c+3)*GD];
        float wb0 = wB[(size_t)(c+0)*GD], wb1 = wB[(size_t)(c+1)*GD];
        float wb2 = wB[(size_t)(c+2)*GD], wb3 = wB[(size_t)(c+3)*GD];
#pragma unroll
        for (int r = 0; r < 4; r++) {
            float4 xv = *(const float4*)&fc[r][c];
            aA[r] += xv.x*wa0 + xv.y*wa1 + xv.z*wa2 + xv.w*wa3;
            aB[r] += xv.x*wb0 + xv.y*wb1 + xv.z*wb2 + xv.w*wb3;
        }
    }
#pragma unroll
    for (int r = 0; r < 4; r++) {
        Y[(size_t)(n0+r)*512 + t]      = aA[r];
        Y[(size_t)(n0+r)*512 + GD + t] = aB[r];
    }
}

// =====================================================================
// edge_qkv: g1 = edge_max(Y1) (stored for residual), then q,k,v = g1@W.
// 4 rows/block, 512 blocks. q pre-scaled by 1/8.
// =====================================================================
__global__ __launch_bounds__(256) void edge_qkv(
    const float* __restrict__ Y, const int* __restrict__ knn,
    const float* __restrict__ b1, const float* __restrict__ Wq,
    const float* __restrict__ Wk, const float* __restrict__ Wv,
    float* __restrict__ g1, float* __restrict__ qb,
    float* __restrict__ kb, float* __restrict__ vb)
{
    int t = threadIdx.x, n0 = blockIdx.x * 4;
    __shared__ int ids[4][DGK];
    __shared__ float xg[4][GD];
    if (t < 4*DGK) {
        int r = t / DGK, j = t - r*DGK;
        int n = n0 + r;
        int base = (n < NSRC) ? 0 : NSRC;
        ids[r][j] = base + knn[n*DGK + j];
    }
    __syncthreads();
#pragma unroll
    for (int r = 0; r < 4; r++) {
        int n = n0 + r;
        float a  = Y[(size_t)n*512 + t];
        float bn = Y[(size_t)n*512 + GD + t];
        float cst = a - bn + b1[t];
        float acc = 0.f;
#pragma unroll
        for (int j = 0; j < DGK; j++) {
            float bj = Y[(size_t)ids[r][j]*512 + GD + t];
            acc = fmaxf(acc, fmaxf(cst + bj, 0.f));
        }
        xg[r][t] = acc;
        g1[(size_t)n*GD + t] = acc;
    }
    __syncthreads();
    const float* Ws[3] = {Wq, Wk, Wv};
    float* outs[3] = {qb, kb, vb};
#pragma unroll
    for (int m = 0; m < 3; m++) {
        const float* W = Ws[m];
        float a[4] = {0.f, 0.f, 0.f, 0.f};
        for (int c = 0; c < GD; c += 4) {
            float w0 = W[(c+0)*GD + t];
            float w1 = W[(c+1)*GD + t];
            float w2 = W[(c+2)*GD + t];
            float w3 = W[(c+3)*GD + t];
#pragma unroll
            for (int r = 0; r < 4; r++) {
                float4 xv = *(const float4*)&xg[r][c];
                a[r] += xv.x*w0 + xv.y*w1 + xv.z*w2 + xv.w*w3;
            }
        }
        float* o = outs[m];
        float s = (m == 0) ? 0.125f : 1.f;
#pragma unroll
        for (int r = 0; r < 4; r++) o[(size_t)(n0+r)*GD + t] = a[r] * s;
    }
}

// =====================================================================
// attention: flash, 8 lanes x 4 rows per unit. TK=16 tile-reg softmax
// + defer-rescale. grid = 16 rg x 4 heads x 8 chunks = 512.
// =====================================================================
__global__ __launch_bounds__(256) void attn_flash(
    const float* __restrict__ qb, const float* __restrict__ kb,
    const float* __restrict__ vb, float* __restrict__ pm,
    float* __restrict__ pl, float* __restrict__ pacc)
{
    int bidx = blockIdx.x;
    int h = bidx & 3, chunk = (bidx >> 2) & 7, rb = bidx >> 5;  // rb 0..15
    int t = threadIdx.x;
    int u = t >> 3, li = t & 7;        // 32 units x 8 lanes
    int row0 = rb * 128 + u * 4;       // 4 consecutive rows per unit
    int kbase = (row0 < NSRC) ? NSRC : 0;

    __shared__ float4 kt[2][TK][16];
    __shared__ float4 vt[2][TK][16];

    const float4* kb4 = (const float4*)kb;
    const float4* vb4 = (const float4*)vb;
    size_t gbase = ((size_t)(kbase + chunk*CHUNK)) * 64 + h*16;

    float4 q[4][2];
#pragma unroll
    for (int r = 0; r < 4; r++) {
        const float4* qp = (const float4*)(qb + (size_t)(row0+r)*GD + h*64 + li*8);
        q[r][0] = qp[0]; q[r][1] = qp[1];
    }
    float4 a[4][2];
#pragma unroll
    for (int r = 0; r < 4; r++) {
        a[r][0] = make_float4(0.f,0.f,0.f,0.f);
        a[r][1] = make_float4(0.f,0.f,0.f,0.f);
    }
    float mr[4], lr[4], p[4][TK];
#pragma unroll
    for (int r = 0; r < 4; r++) { mr[r] = -INFINITY; lr[r] = 0.f; }

    // staging: thread t stages one K float4 and one V float4 per tile.
    int skey = t >> 4, scomp = t & 15;
    float4 rk = kb4[gbase + (size_t)skey*64 + scomp];
    float4 rv = vb4[gbase + (size_t)skey*64 + scomp];
    kt[0][skey][scomp] = rk;
    vt[0][skey][scomp] = rv;
    __syncthreads();

    const int NT = CHUNK / TK;   // 8
    for (int tile = 0; tile < NT; tile++) {
        int cur = tile & 1;
        if (tile + 1 < NT) {
            size_t tb = gbase + (size_t)(tile+1)*TK*64;
            rk = kb4[tb + (size_t)skey*64 + scomp];
            rv = vb4[tb + (size_t)skey*64 + scomp];
        }
        float tm[4];
#pragma unroll
        for (int r = 0; r < 4; r++) tm[r] = -INFINITY;
#pragma unroll
        for (int j = 0; j < TK; j++) {
            float4 k0 = kt[cur][j][li*2+0];
            float4 k1 = kt[cur][j][li*2+1];
#pragma unroll
            for (int r = 0; r < 4; r++) {
                float pp = q[r][0].x*k0.x + q[r][0].y*k0.y + q[r][0].z*k0.z + q[r][0].w*k0.w
                         + q[r][1].x*k1.x + q[r][1].y*k1.y + q[r][1].z*k1.z + q[r][1].w*k1.w;
                pp += __shfl_xor(pp, 1);
                pp += __shfl_xor(pp, 2);
                pp += __shfl_xor(pp, 4);
                p[r][j] = pp;
                tm[r] = fmaxf(tm[r], pp);
            }
        }
#pragma unroll
        for (int r = 0; r < 4; r++) {
            if (tm[r] > mr[r]) {
                float sc = __expf(mr[r] - tm[r]);
                lr[r] *= sc;
                a[r][0].x *= sc; a[r][0].y *= sc; a[r][0].z *= sc; a[r][0].w *= sc;
                a[r][1].x *= sc; a[r][1].y *= sc; a[r][1].z *= sc; a[r][1].w *= sc;
                mr[r] = tm[r];
            }
        }
#pragma unroll
        for (int j = 0; j < TK; j++) {
            float4 v0 = vt[cur][j][li*2+0];
            float4 v1 = vt[cur][j][li*2+1];
#pragma unroll
            for (int r = 0; r < 4; r++) {
                float e = __expf(p[r][j] - mr[r]);
                lr[r] += e;
                a[r][0].x += e*v0.x; a[r][0].y += e*v0.y;
                a[r][0].z += e*v0.z; a[r][0].w += e*v0.w;
                a[r][1].x += e*v1.x; a[r][1].y += e*v1.y;
                a[r][1].z += e*v1.z; a[r][1].w += e*v1.w;
            }
        }
        if (tile + 1 < NT) {
            __syncthreads();
            int nb = (tile + 1) & 1;
            kt[nb][skey][scomp] = rk;
            vt[nb][skey][scomp] = rv;
            __syncthreads();
        }
    }
#pragma unroll
    for (int r = 0; r < 4; r++) {
        int pi = (chunk*4 + h)*NCRS + row0 + r;
        if (li == 0) { pm[pi] = mr[r]; pl[pi] = lr[r]; }
        float4* po = (float4*)(pacc + (size_t)pi*64);
        po[li*2+0] = a[r][0];
        po[li*2+1] = a[r][1];
    }
}

// =====================================================================
// cross_self2: combine attn partials -> msg (LDS), g2 = x+[x,msg]@Wm+bm
// (LDS only), then Y2 = g2 @ [W1|W2]. 4 rows/block, 512 blocks.
// =====================================================================
__global__ __launch_bounds__(256) void cross_self2(
    const float* __restrict__ x, const float* __restrict__ pm,
    const float* __restrict__ pl, const float* __restrict__ pacc,
    const float* __restrict__ Wm, const float* __restrict__ bm,
    const float* __restrict__ Ws, float* __restrict__ Y)
{
    int t = threadIdx.x, n0 = blockIdx.x * 4;
    int h = t >> 6, d = t & 63;
    __shared__ float xs[4][GD], ms[4][GD];
    for (int i = t; i < 4*GD; i += 256) {
        int r = i >> 8, c = i & 255;
        xs[r][c] = x[(size_t)(n0+r)*GD + c];
    }
#pragma unroll
    for (int r = 0; r < 4; r++) {
        int row = n0 + r;
        float m = -INFINITY;
#pragma unroll
        for (int c = 0; c < NCHUNK; c++) m = fmaxf(m, pm[(c*4 + h)*NCRS + row]);
        float lsum = 0.f, asum = 0.f;
#pragma unroll
        for (int c = 0; c < NCHUNK; c++) {
            int pi = (c*4 + h)*NCRS + row;
            float w = __expf(pm[pi] - m);
            lsum += pl[pi] * w;
            asum += pacc[(size_t)pi*64 + d] * w;
        }
        ms[r][t] = asum / lsum;   // t == h*64 + d
    }
    __syncthreads();
    float bv = bm[t];
    float a[4] = {bv, bv, bv, bv};
    for (int c = 0; c < GD; c += 4) {
        float w10 = Wm[(c+0)*GD + t];
        float w11 = Wm[(c+1)*GD + t];
        float w12 = Wm[(c+2)*GD + t];
        float w13 = Wm[(c+3)*GD + t];
        float w20 = Wm[(GD+c+0)*GD + t];
        float w21 = Wm[(GD+c+1)*GD + t];
        float w22 = Wm[(GD+c+2)*GD + t];
        float w23 = Wm[(GD+c+3)*GD + t];
#pragma unroll
        for (int r = 0; r < 4; r++) {
            float4 xv = *(const float4*)&xs[r][c];
            float4 mv = *(const float4*)&ms[r][c];
            a[r] += xv.x*w10 + xv.y*w11 + xv.z*w12 + xv.w*w13
                  + mv.x*w20 + mv.y*w21 + mv.z*w22 + mv.w*w23;
        }
    }
    __syncthreads();               // all ms reads done
#pragma unroll
    for (int r = 0; r < 4; r++) ms[r][t] = xs[r][t] + a[r];   // ms := g2
    __syncthreads();
    float aA[4] = {0.f,0.f,0.f,0.f}, aB[4] = {0.f,0.f,0.f,0.f};
    const float* wA = Ws + t;
    const float* wB = Ws + (size_t)GD*GD + t;
    for (int c = 0; c < GD; c += 4) {
        float wa0 = wA[(size_t)(c+0)*GD], wa1 = wA[(size_t)(c+1)*GD];
        float wa2 = wA[(size_t)(c+2)*GD], wa3 = wA[(size_t)(c+3)*GD];
        float wb0 = wB[(size_t)(c+0)*GD], wb1 = wB[(size_t)(c+1)*GD];
        float wb2 = wB[(size_t)(c+2)*GD], wb3 = wB[(size_t)(c+3)*GD];
#pragma unroll
        for (int r = 0; r < 4; r++) {
            float4 xv = *(const float4*)&ms[r][c];
            aA[r] += xv.x*wa0 + xv.y*wa1 + xv.z*wa2 + xv.w*wa3;
            aB[r] += xv.x*wb0 + xv.y*wb1 + xv.z*wb2 + xv.w*wb3;
        }
    }
#pragma unroll
    for (int r = 0; r < 4; r++) {
        Y[(size_t)(n0+r)*512 + t]      = aA[r];
        Y[(size_t)(n0+r)*512 + GD + t] = aB[r];
    }
}

// =====================================================================
// edge_proj: g3 = edge_max(Y2) (LDS only), feats = g3@Wp + bp,
// then l2norm + score. 4 rows/block, 512 blocks.
// =====================================================================
__global__ __launch_bounds__(256) void edge_proj(
    const float* __restrict__ Y, const int* __restrict__ knn,
    const float* __restrict__ b2, const float* __restrict__ Wp,
    const float* __restrict__ bp, const float* __restrict__ Wsc,
    const float* __restrict__ bsc, float* __restrict__ feats,
    float* __restrict__ fnorm, float* __restrict__ scores)
{
    int t = threadIdx.x, n0 = blockIdx.x * 4;
    __shared__ int ids[4][DGK];
    __shared__ float xg[4][GD];
    __shared__ float pf[4][GD];
    if (t < 4*DGK) {
        int r = t / DGK, j = t - r*DGK;
        int n = n0 + r;
        int base = (n < NSRC) ? 0 : NSRC;
        ids[r][j] = base + knn[n*DGK + j];
    }
    __syncthreads();
#pragma unroll
    for (int r = 0; r < 4; r++) {
        int n = n0 + r;
        float a  = Y[(size_t)n*512 + t];
        float bn = Y[(size_t)n*512 + GD + t];
        float cst = a - bn + b2[t];
        float acc = 0.f;
#pragma unroll
        for (int j = 0; j < DGK; j++) {
            float bj = Y[(size_t)ids[r][j]*512 + GD + t];
            acc = fmaxf(acc, fmaxf(cst + bj, 0.f));
        }
        xg[r][t] = acc;
    }
    __syncthreads();
    float a[4] = {0.f, 0.f, 0.f, 0.f};
    for (int c = 0; c < GD; c += 4) {
        float w0 = Wp[(c+0)*GD + t];
        float w1 = Wp[(c+1)*GD + t];
        float w2 = Wp[(c+2)*GD + t];
        float w3 = Wp[(c+3)*GD + t];
#pragma unroll
        for (int r = 0; r < 4; r++) {
            float4 xv = *(const float4*)&xg[r][c];
            a[r] += xv.x*w0 + xv.y*w1 + xv.z*w2 + xv.w*w3;
        }
    }
    float bv = bp[t];
#pragma unroll
    for (int r = 0; r < 4; r++) {
        float v = a[r] + bv;
        feats[(size_t)(n0+r)*GD + t] = v;
        pf[r][t] = v;
    }
    __syncthreads();
    int lane = t & 63, w = t >> 6;     // wave w handles row w
    int rr = n0 + w;
    float q0 = pf[w][lane], q1 = pf[w][64+lane], q2 = pf[w][128+lane], q3 = pf[w][192+lane];
    float sq = q0*q0 + q1*q1 + q2*q2 + q3*q3;
    float sc = q0*Wsc[lane] + q1*Wsc[64+lane] + q2*Wsc[128+lane] + q3*Wsc[192+lane];
#pragma unroll
    for (int off = 32; off >= 1; off >>= 1) {
        sq += __shfl_xor(sq, off);
        sc += __shfl_xor(sc, off);
    }
    float inv = 1.f / fmaxf(sqrtf(sq), 1e-12f);
    fnorm[(size_t)rr*GD + lane]       = q0*inv;
    fnorm[(size_t)rr*GD + 64 + lane]  = q1*inv;
    fnorm[(size_t)rr*GD + 128 + lane] = q2*inv;
    fnorm[(size_t)rr*GD + 192 + lane] = q3*inv;
    if (lane == 0) scores[rr] = sc + bsc[0];
}

// ip: 4 src rows x 256 tgt cols per block; grid 1024
__global__ __launch_bounds__(256) void ip_kernel(
    const float* __restrict__ fnorm, float* __restrict__ ip)
{
    int t = threadIdx.x;
    int n0 = (blockIdx.x >> 2) * 4;
    int m  = (blockIdx.x & 3) * 256 + t;
    __shared__ float xs[GD][4];
    for (int i = t; i < 4*GD; i += 256) {
        int r = i >> 8, c = i & 255;
        xs[c][r] = fnorm[(size_t)(n0+r)*GD + c];
    }
    __syncthreads();
    const float4* fr = (const float4*)(fnorm + (size_t)(NSRC + m)*GD);
    float a0 = 0.f, a1 = 0.f, a2 = 0.f, a3 = 0.f;
    for (int c4 = 0; c4 < GD/4; c4++) {
        float4 f = fr[c4];
        float4 xa = *(const float4*)&xs[c4*4+0][0];
        float4 xb = *(const float4*)&xs[c4*4+1][0];
        float4 xc = *(const float4*)&xs[c4*4+2][0];
        float4 xd = *(const float4*)&xs[c4*4+3][0];
        a0 += f.x*xa.x + f.y*xb.x + f.z*xc.x + f.w*xd.x;
        a1 += f.x*xa.y + f.y*xb.y + f.z*xc.y + f.w*xd.y;
        a2 += f.x*xa.z + f.y*xb.z + f.z*xc.z + f.w*xd.z;
        a3 += f.x*xa.w + f.y*xb.w + f.z*xc.w + f.w*xd.w;
    }
    ip[(size_t)(n0+0)*NSRC + m] = a0;
    ip[(size_t)(n0+1)*NSRC + m] = a1;
    ip[(size_t)(n0+2)*NSRC + m] = a2;
    ip[(size_t)(n0+3)*NSRC + m] = a3;
}

// =====================================================================
// saliency + dec_coarse fused: block g computes sal[g], then
// decfeat[g][:] = bd + scores[g]*Wd0 + sal[g]*Wd1 + feats[g]·Wd[2:258].
// =====================================================================
__global__ __launch_bounds__(256) void saliency_dec(
    const float* __restrict__ ip, const float* __restrict__ scores,
    const float* __restrict__ epsv, const float* __restrict__ feats,
    const float* __restrict__ Wd, const float* __restrict__ bd,
    float* __restrict__ sal_out, float* __restrict__ decfeat)
{
    int g = blockIdx.x, t = threadIdx.x;
    bool col = (g >= NSRC);
    int n = col ? (g - NSRC) : g;
    const float* so = col ? scores : (scores + NSRC);
    float T = expf(epsv[0]) + 0.03f;
    __shared__ float red[256];
    __shared__ float fr[GD];
    __shared__ float salv;
    for (int c = t; c < GD; c += 256) fr[c] = feats[(size_t)g*GD + c];
    float vals[4];
    float m = -INFINITY;
#pragma unroll
    for (int ii = 0; ii < 4; ii++) {
        int i = t + ii*256;
        float vv = col ? ip[(size_t)i*NSRC + n] : ip[(size_t)n*NSRC + i];
        vv /= T;
        vals[ii] = vv;
        m = fmaxf(m, vv);
    }
    red[t] = m; __syncthreads();
    for (int s = 128; s > 0; s >>= 1) { if (t < s) red[t] = fmaxf(red[t], red[t+s]); __syncthreads(); }
    float mx = red[0]; __syncthreads();
    float se = 0.f, wsum = 0.f;
#pragma unroll
    for (int ii = 0; ii < 4; ii++) {
        int i = t + ii*256;
        float e = expf(vals[ii] - mx);
        se += e; wsum += e * so[i];
    }
    red[t] = se; __syncthreads();
    for (int s = 128; s > 0; s >>= 1) { if (t < s) red[t] += red[t+s]; __syncthreads(); }
    float S = red[0]; __syncthreads();
    red[t] = wsum; __syncthreads();
    for (int s = 128; s > 0; s >>= 1) { if (t < s) red[t] += red[t+s]; __syncthreads(); }
    if (t == 0) {
        float v = red[0] / S;
        sal_out[g] = v;
        salv = v;
    }
    __syncthreads();
    if (t < 40) {
        float acc = 0.f;
        if (t < DECOUT) {
            acc = bd[t] + scores[g]*Wd[t] + salv*Wd[DECOUT + t];
            for (int c = 0; c < GD; c++) acc += fr[c] * Wd[(2 + c)*DECOUT + t];
        }
        decfeat[(size_t)g*40 + t] = acc;
    }
}

// =====================================================================
// decoder — thread per row: acc = decfeat[u] + skip@Wskip (LDS, padded 36)
// =====================================================================
__global__ __launch_bounds__(256) void decoder_kernel(
    const float* __restrict__ decfeat, const float* __restrict__ skip,
    const int* __restrict__ ups, const float* __restrict__ Wd,
    float* __restrict__ outf, float* __restrict__ outso,
    float* __restrict__ outss)
{
    int t = threadIdx.x;
    __shared__ float wsk[C1D*36];   // 18432 B
    for (int i = t; i < C1D*36; i += 256) {
        int cc = i / 36, j = i - cc*36;
        wsk[i] = (j < DECOUT) ? Wd[(size_t)(2 + GD + cc)*DECOUT + j] : 0.f;
    }
    __syncthreads();
    int row = blockIdx.x * 256 + t;
    if (row >= NFINE) return;
    int u = ups[row];
    float4 acc[9];
    const float4* df = (const float4*)(decfeat + (size_t)u*40);
#pragma unroll
    for (int q = 0; q < 9; q++) acc[q] = df[q];
    const float4* sr = (const float4*)(skip + (size_t)row*C1D);
    for (int c4 = 0; c4 < C1D/4; c4++) {
        float4 xv = sr[c4];
        const float* wb = wsk + c4*4*36;
#pragma unroll
        for (int q = 0; q < 9; q++) {
            float4 w0 = *(const float4*)&wb[q*4];
            float4 w1 = *(const float4*)&wb[36 + q*4];
            float4 w2 = *(const float4*)&wb[72 + q*4];
            float4 w3 = *(const float4*)&wb[108 + q*4];
            acc[q].x += xv.x*w0.x + xv.y*w1.x + xv.z*w2.x + xv.w*w3.x;
            acc[q].y += xv.x*w0.y + xv.y*w1.y + xv.z*w2.y + xv.w*w3.y;
            acc[q].z += xv.x*w0.z + xv.y*w1.z + xv.z*w2.z + xv.w*w3.z;
            acc[q].w += xv.x*w0.w + xv.y*w1.w + xv.z*w2.w + xv.w*w3.w;
        }
    }
    float sq = 0.f;
#pragma unroll
    for (int q = 0; q < 8; q++)
        sq += acc[q].x*acc[q].x + acc[q].y*acc[q].y + acc[q].z*acc[q].z + acc[q].w*acc[q].w;
    float inv = 1.f / fmaxf(sqrtf(sq), 1e-12f);
    float4* op = (float4*)(outf + (size_t)row*FINALD);
#pragma unroll
    for (int q = 0; q < 8; q++)
        op[q] = make_float4(acc[q].x*inv, acc[q].y*inv, acc[q].z*inv, acc[q].w*inv);
    float so = 1.f/(1.f + __expf(-acc[8].x));
    so = fminf(fmaxf(so, 0.f), 1.f); if (!(so == so)) so = 0.f;
    float ss = 1.f/(1.f + __expf(-acc[8].y));
    ss = fminf(fmaxf(ss, 0.f), 1.f); if (!(ss == ss)) ss = 0.f;
    outso[row] = so; outss[row] = ss;
}

// =====================================================================
extern "C" void kernel_launch(void* const* d_in, const int* in_sizes, int n_in,
                              void* d_out, int out_size, void* d_ws, size_t ws_size,
                              hipStream_t stream)
{
    const float* points_f     = (const float*)d_in[0];
    const float* points_c     = (const float*)d_in[1];
    const float* features     = (const float*)d_in[2];
    const float* kp_f         = (const float*)d_in[3];
    const float* kp_c         = (const float*)d_in[4];
    const float* W_kp1        = (const float*)d_in[5];
    const float* W_kp2        = (const float*)d_in[6];
    const float* W_bottle     = (const float*)d_in[7];
    const float* b_bottle     = (const float*)d_in[8];
    const float* W_self1      = (const float*)d_in[9];
    const float* b_self1      = (const float*)d_in[10];
    const float* Wq           = (const float*)d_in[11];
    const float* Wk           = (const float*)d_in[12];
    const float* Wv           = (const float*)d_in[13];
    const float* W_cross      = (const float*)d_in[14];
    const float* b_cross      = (const float*)d_in[15];
    const float* W_self2      = (const float*)d_in[16];
    const float* b_self2      = (const float*)d_in[17];
    const float* W_proj       = (const float*)d_in[18];
    const float* b_proj       = (const float*)d_in[19];
    const float* W_score      = (const float*)d_in[20];
    const float* b_score      = (const float*)d_in[21];
    const float* epsilon      = (const float*)d_in[22];
    const float* W_dec        = (const float*)d_in[23];
    const float* b_dec        = (const float*)d_in[24];
    const int*   neighbors_f  = (const int*)d_in[25];
    const int*   pool_idx     = (const int*)d_in[26];
    const int*   upsample_idx = (const int*)d_in[27];

    float* ws = (float*)d_ws;
    size_t o = 0;
    auto alloc = [&](size_t nfl) { float* p = ws + o; o += (nfl + 63) & ~(size_t)63; return p; };
    float* x_f     = alloc((size_t)NFINE * C1D);
    float* g1      = alloc((size_t)NCRS * GD);
    float* qb      = alloc((size_t)NCRS * GD);
    float* kb      = alloc((size_t)NCRS * GD);
    float* vb      = alloc((size_t)NCRS * GD);
    float* scores  = alloc(NCRS);
    float* sal     = alloc(NCRS);
    float* decfeat = alloc((size_t)NCRS * 40);
    int*   knn_b   = (int*)alloc(NCRS * DGK);

    // Union region: phases reuse the same memory (lifetimes are disjoint).
    const size_t NG  = (size_t)NCRS * GD;           // 524288
    const size_t MN  = (size_t)NCRS * C2D;          // 524288
    const size_t PMN = (size_t)NCRS * 4 * NCHUNK;   // 65536
    size_t usz = 4*MN + (size_t)NCRS*KP*C1D;        // 6,029,312 (covers all phases)
    float* U = alloc(usz);
    // encoder: pbuf [hh_gemm -> bottle_self1), hhg [hh_kernel -> hh_gemm)
    float* pbuf = U;
    float* hhg  = U + 4*MN;
    // Y1 written by bottle_self1 (hhg dead), read by edge_qkv
    float* Y1   = U + 4*MN;
    // attention partials [attn -> cross_self2)
    float* pm   = U;
    float* pl   = U + PMN;
    float* pacc = U + 2*PMN;
    // Y2 coexists with partials in cross_self2
    float* Y2   = U + 2*PMN + PMN*64;
    // head phase (partials dead; Y2 read by edge_proj)
    float* feats = U;                               // [0, NG)
    float* fnorm = U + NG;                          // [NG, 2NG)
    float* ip    = U + 2*NG;                        // [2NG, 4NG)

    float* outf  = (float*)d_out;
    float* outso = outf + (size_t)NFINE * FINALD;
    float* outss = outso + NFINE;

    // encoder (+ independent knn fused into the same launch)
    fine_knn<<<FINEB + NCRS, 256, 0, stream>>>(points_f, features, neighbors_f, kp_f,
                                               W_kp1, x_f, points_c, knn_b);
    hh_kernel<<<NCRS, 256, 0, stream>>>(points_c, points_f, x_f, pool_idx, kp_c, hhg);
    hh_gemm<<<(NCRS/GTR)*KC, 256, 0, stream>>>(hhg, W_kp2, pbuf);
    bottle_self1<<<NCRS/4, 256, 0, stream>>>(pbuf, W_bottle, b_bottle, W_self1, Y1);

    // GNN
    edge_qkv<<<NCRS/4, 256, 0, stream>>>(Y1, knn_b, b_self1, Wq, Wk, Wv, g1, qb, kb, vb);
    attn_flash<<<512, 256, 0, stream>>>(qb, kb, vb, pm, pl, pacc);
    cross_self2<<<NCRS/4, 256, 0, stream>>>(g1, pm, pl, pacc, W_cross, b_cross, W_self2, Y2);
    edge_proj<<<NCRS/4, 256, 0, stream>>>(Y2, knn_b, b_self2, W_proj, b_proj,
                                          W_score, b_score, feats, fnorm, scores);

    // head
    ip_kernel<<<NSRC, 256, 0, stream>>>(fnorm, ip);
    saliency_dec<<<NCRS, 256, 0, stream>>>(ip, scores, epsilon, feats, W_dec, b_dec,
                                           sal, decfeat);

    // decoder
    decoder_kernel<<<(NFINE + 255)/256, 256, 0, stream>>>(decfeat, x_f, upsample_idx,
                                                          W_dec, outf, outso, outss);
}

// Round 15
// 416.656 us; speedup vs baseline: 1.0530x; 1.0530x over previous
//
#include <hip/hip_runtime.h>
#include <math.h>

// ---- problem constants ----
#define NFINE   80000
#define NCRS    2048
#define NSRC    1024
#define NNB     30
#define KP      15
#define C1D     128
#define C2D     256
#define GD      256
#define DGK     10
#define FINALD  32
#define DECOUT  34

#define NCHUNK  8      // attention key-split
#define CHUNK   128    // 1024 / NCHUNK
#define TK      8      // attention LDS key tile (register-scored)
#define KC      4      // hh-gemm K chunks
#define KSTEP   480    // 1920 / KC
#define GTR     16     // hh-gemm rows per block
#define FINEB   10000  // kpconv_fine blocks (8 points each)

// =====================================================================
// fused kpconv_fine (blocks 0..9999) + knn (blocks 10000..12047)
// =====================================================================
__global__ __launch_bounds__(256) void fine_knn(
    const float* __restrict__ pts, const float* __restrict__ feat,
    const int* __restrict__ nbr, const float* __restrict__ kp,
    const float* __restrict__ W, float* __restrict__ out,
    const float* __restrict__ pc, int* __restrict__ knn)
{
    __shared__ float contrib[8][NNB][17];
    __shared__ float h[8][KP + 1];
    __shared__ float d2s[NSRC];
    __shared__ float wval[4];
    __shared__ int   widx[4];
    int t = threadIdx.x;
    if (blockIdx.x < FINEB) {
        int w = t >> 6, lane = t & 63;
        int half = lane >> 5, hl = lane & 31;
        int pslot = w*2 + half;
        int n = blockIdx.x * 8 + pslot;
        float kx[KP], ky[KP], kz[KP], kk[KP];
#pragma unroll
        for (int k = 0; k < KP; k++) {
            kx[k] = kp[k*3]; ky[k] = kp[k*3+1]; kz[k] = kp[k*3+2];
            kk[k] = kx[k]*kx[k] + ky[k]*ky[k] + kz[k]*kz[k];
        }
        if (hl < NNB) {
            float qx = pts[n*3], qy = pts[n*3+1], qz = pts[n*3+2];
            int id = nbr[n*NNB + hl];
            float rx = pts[id*3]-qx, ry = pts[id*3+1]-qy, rz = pts[id*3+2]-qz;
            float rr = rx*rx + ry*ry + rz*rz;
            float f = feat[id];
#pragma unroll
            for (int k = 0; k < KP; k++) {
                float d2 = rr + kk[k] - 2.f*(rx*kx[k] + ry*ky[k] + rz*kz[k]);
                float infl = fmaxf(1.f - sqrtf(fmaxf(d2, 1e-12f)), 0.f); // extent=1
                contrib[pslot][hl][k] = infl * f;
            }
        }
        __syncthreads();
        if (hl < KP) {
            float s = 0.f;
#pragma unroll
            for (int j = 0; j < NNB; j++) s += contrib[pslot][j][hl];
            h[pslot][hl] = s;
        }
        __syncthreads();
        int nA = blockIdx.x * 8 + w*2;
        float a0 = 0.f, a1 = 0.f, b0 = 0.f, b1 = 0.f;
#pragma unroll
        for (int k = 0; k < KP; k++) {
            float w0 = W[k*C1D + lane];
            float w1 = W[k*C1D + 64 + lane];
            float hA = h[w*2][k], hB = h[w*2+1][k];
            a0 += hA*w0; a1 += hA*w1;
            b0 += hB*w0; b1 += hB*w1;
        }
        out[(size_t)nA*C1D + lane]          = a0;
        out[(size_t)nA*C1D + 64 + lane]     = a1;
        out[(size_t)(nA+1)*C1D + lane]      = b0;
        out[(size_t)(nA+1)*C1D + 64 + lane] = b1;
    } else {
        int g = blockIdx.x - FINEB;       // query 0..2047
        int base = (g < NSRC) ? 0 : NSRC;
        int local = g - base;
        const float* P = pc + (size_t)base*3;
        float qx = P[local*3], qy = P[local*3+1], qz = P[local*3+2];
        float sqn = qx*qx + qy*qy + qz*qz;
#pragma unroll
        for (int ii = 0; ii < 4; ii++) {
            int m = t + ii*256;
            float px = P[m*3], py = P[m*3+1], pz = P[m*3+2];
            float sqm = px*px + py*py + pz*pz;
            d2s[m] = sqn + sqm - 2.f*(qx*px + qy*py + qz*pz);
        }
        __syncthreads();
        for (int r = 0; r < DGK; r++) {
            float bv = 3.4e38f; int bidx = NSRC;
#pragma unroll
            for (int ii = 0; ii < 4; ii++) {
                int m = t + ii*256;
                float v = d2s[m];
                if (v < bv) { bv = v; bidx = m; }   // ascending m: ties keep lower
            }
#pragma unroll
            for (int off = 32; off >= 1; off >>= 1) {
                float ov = __shfl_xor(bv, off);
                int   oi = __shfl_xor(bidx, off);
                if (ov < bv || (ov == bv && oi < bidx)) { bv = ov; bidx = oi; }
            }
            if ((t & 63) == 0) { wval[t >> 6] = bv; widx[t >> 6] = bidx; }
            __syncthreads();
            if (t == 0) {
                float fv = wval[0]; int fi = widx[0];
#pragma unroll
                for (int wv2 = 1; wv2 < 4; wv2++)
                    if (wval[wv2] < fv || (wval[wv2] == fv && widx[wv2] < fi)) {
                        fv = wval[wv2]; fi = widx[wv2];
                    }
                knn[g*DGK + r] = fi;
                d2s[fi] = 3.4e38f;
            }
            __syncthreads();
        }
    }
}

// =====================================================================
// hh for each coarse point -> global
// =====================================================================
__global__ __launch_bounds__(256) void hh_kernel(
    const float* __restrict__ pc, const float* __restrict__ pf,
    const float* __restrict__ xf, const int* __restrict__ pool,
    const float* __restrict__ kp, float* __restrict__ hhg)
{
    int n = blockIdx.x, t = threadIdx.x;
    __shared__ float kx[KP], ky[KP], kz[KP], kk[KP];
    __shared__ float rel[NNB][4];
    __shared__ int   ids[NNB];
    __shared__ float infl[NNB][KP + 1];
    __shared__ float nf[NNB][C1D];
    if (t < KP) {
        float a = kp[t*3], b = kp[t*3+1], c = kp[t*3+2];
        kx[t] = a; ky[t] = b; kz[t] = c; kk[t] = a*a + b*b + c*c;
    }
    if (t < NNB) {
        int id = pool[n*NNB + t]; ids[t] = id;
        float qx = pc[n*3], qy = pc[n*3+1], qz = pc[n*3+2];
        float rx = pf[id*3]-qx, ry = pf[id*3+1]-qy, rz = pf[id*3+2]-qz;
        rel[t][0] = rx; rel[t][1] = ry; rel[t][2] = rz;
        rel[t][3] = rx*rx + ry*ry + rz*rz;
    }
    __syncthreads();
    for (int i = t; i < NNB*KP; i += 256) {
        int j = i / KP, kq = i % KP;
        float d2 = rel[j][3] + kk[kq]
                 - 2.f*(rel[j][0]*kx[kq] + rel[j][1]*ky[kq] + rel[j][2]*kz[kq]);
        infl[j][kq] = fmaxf(1.f - sqrtf(fmaxf(d2, 1e-12f)) * 0.5f, 0.f); // extent=2
    }
    for (int i = t; i < NNB*C1D; i += 256) {
        int j = i >> 7, c = i & 127;
        nf[j][c] = xf[(size_t)ids[j]*C1D + c];
    }
    __syncthreads();
    for (int i = t; i < KP*C1D; i += 256) {
        int kq = i >> 7, c = i & 127;
        float s = 0.f;
#pragma unroll
        for (int j = 0; j < NNB; j++) s += infl[j][kq] * nf[j][c];
        hhg[(size_t)n*(KP*C1D) + i] = s;
    }
}

// =====================================================================
// hh GEMM split-K: block = (16 rows, 480-K chunk). partials to pbuf.
// =====================================================================
__global__ __launch_bounds__(256) void hh_gemm(
    const float* __restrict__ hhg, const float* __restrict__ W,
    float* __restrict__ pbuf)
{
    int t = threadIdx.x;
    int rg = blockIdx.x >> 2, kc = blockIdx.x & 3;
    int n0 = rg * GTR, kb0 = kc * KSTEP;
    __shared__ float xi[GTR][KSTEP];   // 30720 B, row-major
    float* xf = &xi[0][0];
    for (int i = t; i < GTR*KSTEP; i += 256) {
        int r = i / KSTEP, c = i - r*KSTEP;
        xf[i] = hhg[(size_t)(n0 + r)*(KP*C1D) + kb0 + c];
    }
    __syncthreads();
    float a[GTR];
#pragma unroll
    for (int r = 0; r < GTR; r++) a[r] = 0.f;
    for (int c = 0; c < KSTEP; c += 4) {
        float w0 = W[(size_t)(kb0+c+0)*C2D + t];
        float w1 = W[(size_t)(kb0+c+1)*C2D + t];
        float w2 = W[(size_t)(kb0+c+2)*C2D + t];
        float w3 = W[(size_t)(kb0+c+3)*C2D + t];
#pragma unroll
        for (int r = 0; r < GTR; r++) {
            float4 xv = *(const float4*)&xi[r][c];
            a[r] += xv.x*w0 + xv.y*w1 + xv.z*w2 + xv.w*w3;
        }
    }
#pragma unroll
    for (int r = 0; r < GTR; r++)
        pbuf[(size_t)kc*NCRS*C2D + (size_t)(n0+r)*C2D + t] = a[r];
}

// =====================================================================
// bottle_self1: feats_c = (sum_kc pbuf)@Wb + bb  (kept in LDS only),
// then Y1 = feats_c @ [W1|W2]. 4 rows/block, 512 blocks, 256 thr.
// =====================================================================
__global__ __launch_bounds__(256) void bottle_self1(
    const float* __restrict__ pbuf, const float* __restrict__ Wb,
    const float* __restrict__ bb, const float* __restrict__ Ws,
    float* __restrict__ Y)
{
    int t = threadIdx.x, n0 = blockIdx.x * 4;
    const size_t MN = (size_t)NCRS*C2D;
    __shared__ float xi[4][C2D];
    __shared__ float fc[4][C2D];
    for (int i = t; i < 4*C2D; i += 256) {
        int r = i >> 8, c = i & 255;
        size_t off = (size_t)(n0+r)*C2D + c;
        xi[r][c] = pbuf[off] + pbuf[MN+off] + pbuf[2*MN+off] + pbuf[3*MN+off];
    }
    __syncthreads();
    {
        float a[4] = {0.f, 0.f, 0.f, 0.f};
        for (int c = 0; c < C2D; c += 4) {
            float w0 = Wb[(c+0)*GD + t];
            float w1 = Wb[(c+1)*GD + t];
            float w2 = Wb[(c+2)*GD + t];
            float w3 = Wb[(c+3)*GD + t];
#pragma unroll
            for (int r = 0; r < 4; r++) {
                float4 xv = *(const float4*)&xi[r][c];
                a[r] += xv.x*w0 + xv.y*w1 + xv.z*w2 + xv.w*w3;
            }
        }
        float bv = bb[t];
#pragma unroll
        for (int r = 0; r < 4; r++) fc[r][t] = a[r] + bv;
    }
    __syncthreads();
    float aA[4] = {0.f,0.f,0.f,0.f}, aB[4] = {0.f,0.f,0.f,0.f};
    const float* wA = Ws + t;
    const float* wB = Ws + (size_t)GD*GD + t;
    for (int c = 0; c < GD; c += 4) {
        float wa0 = wA[(size_t)(c+0)*GD], wa1 = wA[(size_t)(c+1)*GD];
        float wa2 = wA[(size_t)(c+2)*GD], wa3 = wA[(size_t)(c+3)*GD];
        float wb0 = wB[(size_t)(c+0)*GD], wb1 = wB[(size_t)(c+1)*GD];
        float wb2 = wB[(size_t)(c+2)*GD], wb3 = wB[(size_t)(c+3)*GD];
#pragma unroll
        for (int r = 0; r < 4; r++) {
            float4 xv = *(const float4*)&fc[r][c];
            aA[r] += xv.x*wa0 + xv.y*wa1 + xv.z*wa2 + xv.w*wa3;
            aB[r] += xv.x*wb0 + xv.y*wb1 + xv.z*wb2 + xv.w*wb3;
        }
    }
#pragma unroll
    for (int r = 0; r < 4; r++) {
        Y[(size_t)(n0+r)*512 + t]      = aA[r];
        Y[(size_t)(n0+r)*512 + GD + t] = aB[r];
    }
}

// =====================================================================
// edge_qkv: g1 = edge_max(Y1) (stored for residual), then q,k,v = g1@W.
// 4 rows/block, 512 blocks. q pre-scaled by 1/8.
// =====================================================================
__global__ __launch_bounds__(256) void edge_qkv(
    const float* __restrict__ Y, const int* __restrict__ knn,
    const float* __restrict__ b1, const float* __restrict__ Wq,
    const float* __restrict__ Wk, const float* __restrict__ Wv,
    float* __restrict__ g1, float* __restrict__ qb,
    float* __restrict__ kb, float* __restrict__ vb)
{
    int t = threadIdx.x, n0 = blockIdx.x * 4;
    __shared__ int ids[4][DGK];
    __shared__ float xg[4][GD];
    if (t < 4*DGK) {
        int r = t / DGK, j = t - r*DGK;
        int n = n0 + r;
        int base = (n < NSRC) ? 0 : NSRC;
        ids[r][j] = base + knn[n*DGK + j];
    }
    __syncthreads();
#pragma unroll
    for (int r = 0; r < 4; r++) {
        int n = n0 + r;
        float a  = Y[(size_t)n*512 + t];
        float bn = Y[(size_t)n*512 + GD + t];
        float cst = a - bn + b1[t];
        float acc = 0.f;
#pragma unroll
        for (int j = 0; j < DGK; j++) {
            float bj = Y[(size_t)ids[r][j]*512 + GD + t];
            acc = fmaxf(acc, fmaxf(cst + bj, 0.f));
        }
        xg[r][t] = acc;
        g1[(size_t)n*GD + t] = acc;
    }
    __syncthreads();
    const float* Ws[3] = {Wq, Wk, Wv};
    float* outs[3] = {qb, kb, vb};
#pragma unroll
    for (int m = 0; m < 3; m++) {
        const float* W = Ws[m];
        float a[4] = {0.f, 0.f, 0.f, 0.f};
        for (int c = 0; c < GD; c += 4) {
            float w0 = W[(c+0)*GD + t];
            float w1 = W[(c+1)*GD + t];
            float w2 = W[(c+2)*GD + t];
            float w3 = W[(c+3)*GD + t];
#pragma unroll
            for (int r = 0; r < 4; r++) {
                float4 xv = *(const float4*)&xg[r][c];
                a[r] += xv.x*w0 + xv.y*w1 + xv.z*w2 + xv.w*w3;
            }
        }
        float* o = outs[m];
        float s = (m == 0) ? 0.125f : 1.f;
#pragma unroll
        for (int r = 0; r < 4; r++) o[(size_t)(n0+r)*GD + t] = a[r] * s;
    }
}

// =====================================================================
// attention: flash, 8 lanes x 4 rows per unit. TK=8 tile-reg softmax
// + defer-rescale. grid = 16 rg x 4 heads x 8 chunks = 512.
// =====================================================================
__global__ __launch_bounds__(256) void attn_flash(
    const float* __restrict__ qb, const float* __restrict__ kb,
    const float* __restrict__ vb, float* __restrict__ pm,
    float* __restrict__ pl, float* __restrict__ pacc)
{
    int bidx = blockIdx.x;
    int h = bidx & 3, chunk = (bidx >> 2) & 7, rb = bidx >> 5;  // rb 0..15
    int t = threadIdx.x;
    int u = t >> 3, li = t & 7;        // 32 units x 8 lanes
    int row0 = rb * 128 + u * 4;       // 4 consecutive rows per unit
    int kbase = (row0 < NSRC) ? NSRC : 0;

    __shared__ float4 kt[2][TK][16];
    __shared__ float4 vt[2][TK][16];

    const float4* kb4 = (const float4*)kb;
    const float4* vb4 = (const float4*)vb;
    size_t gbase = ((size_t)(kbase + chunk*CHUNK)) * 64 + h*16;

    float4 q[4][2];
#pragma unroll
    for (int r = 0; r < 4; r++) {
        const float4* qp = (const float4*)(qb + (size_t)(row0+r)*GD + h*64 + li*8);
        q[r][0] = qp[0]; q[r][1] = qp[1];
    }
    float4 a[4][2];
#pragma unroll
    for (int r = 0; r < 4; r++) {
        a[r][0] = make_float4(0.f,0.f,0.f,0.f);
        a[r][1] = make_float4(0.f,0.f,0.f,0.f);
    }
    float mr[4], lr[4], p[4][TK];
#pragma unroll
    for (int r = 0; r < 4; r++) { mr[r] = -INFINITY; lr[r] = 0.f; }

    // staging: thread t stages 1 float4/tile. t<128: K, t>=128: V.
    int half = t >> 7, sidx = t & 127, skey = sidx >> 4, scomp = sidx & 15;
    const float4* sb = half ? vb4 : kb4;
    float4 rs = sb[gbase + (size_t)skey*64 + scomp];
    if (half) vt[0][skey][scomp] = rs; else kt[0][skey][scomp] = rs;
    __syncthreads();

    const int NT = CHUNK / TK;   // 16
    for (int tile = 0; tile < NT; tile++) {
        int cur = tile & 1;
        if (tile + 1 < NT)
            rs = sb[gbase + (size_t)(tile+1)*TK*64 + (size_t)skey*64 + scomp];
        float tm[4];
#pragma unroll
        for (int r = 0; r < 4; r++) tm[r] = -INFINITY;
#pragma unroll
        for (int j = 0; j < TK; j++) {
            float4 k0 = kt[cur][j][li*2+0];
            float4 k1 = kt[cur][j][li*2+1];
#pragma unroll
            for (int r = 0; r < 4; r++) {
                float pp = q[r][0].x*k0.x + q[r][0].y*k0.y + q[r][0].z*k0.z + q[r][0].w*k0.w
                         + q[r][1].x*k1.x + q[r][1].y*k1.y + q[r][1].z*k1.z + q[r][1].w*k1.w;
                pp += __shfl_xor(pp, 1);
                pp += __shfl_xor(pp, 2);
                pp += __shfl_xor(pp, 4);
                p[r][j] = pp;
                tm[r] = fmaxf(tm[r], pp);
            }
        }
#pragma unroll
        for (int r = 0; r < 4; r++) {
            if (tm[r] > mr[r]) {
                float sc = __expf(mr[r] - tm[r]);
                lr[r] *= sc;
                a[r][0].x *= sc; a[r][0].y *= sc; a[r][0].z *= sc; a[r][0].w *= sc;
                a[r][1].x *= sc; a[r][1].y *= sc; a[r][1].z *= sc; a[r][1].w *= sc;
                mr[r] = tm[r];
            }
        }
#pragma unroll
        for (int j = 0; j < TK; j++) {
            float4 v0 = vt[cur][j][li*2+0];
            float4 v1 = vt[cur][j][li*2+1];
#pragma unroll
            for (int r = 0; r < 4; r++) {
                float e = __expf(p[r][j] - mr[r]);
                lr[r] += e;
                a[r][0].x += e*v0.x; a[r][0].y += e*v0.y;
                a[r][0].z += e*v0.z; a[r][0].w += e*v0.w;
                a[r][1].x += e*v1.x; a[r][1].y += e*v1.y;
                a[r][1].z += e*v1.z; a[r][1].w += e*v1.w;
            }
        }
        if (tile + 1 < NT) {
            __syncthreads();
            if (half) vt[(tile+1)&1][skey][scomp] = rs;
            else      kt[(tile+1)&1][skey][scomp] = rs;
            __syncthreads();
        }
    }
#pragma unroll
    for (int r = 0; r < 4; r++) {
        int pi = (chunk*4 + h)*NCRS + row0 + r;
        if (li == 0) { pm[pi] = mr[r]; pl[pi] = lr[r]; }
        float4* po = (float4*)(pacc + (size_t)pi*64);
        po[li*2+0] = a[r][0];
        po[li*2+1] = a[r][1];
    }
}

// =====================================================================
// cross_self2: combine attn partials -> msg (LDS), g2 = x+[x,msg]@Wm+bm
// (LDS only), then Y2 = g2 @ [W1|W2]. 4 rows/block, 512 blocks.
// =====================================================================
__global__ __launch_bounds__(256) void cross_self2(
    const float* __restrict__ x, const float* __restrict__ pm,
    const float* __restrict__ pl, const float* __restrict__ pacc,
    const float* __restrict__ Wm, const float* __restrict__ bm,
    const float* __restrict__ Ws, float* __restrict__ Y)
{
    int t = threadIdx.x, n0 = blockIdx.x * 4;
    int h = t >> 6, d = t & 63;
    __shared__ float xs[4][GD], ms[4][GD];
    for (int i = t; i < 4*GD; i += 256) {
        int r = i >> 8, c = i & 255;
        xs[r][c] = x[(size_t)(n0+r)*GD + c];
    }
#pragma unroll
    for (int r = 0; r < 4; r++) {
        int row = n0 + r;
        float m = -INFINITY;
#pragma unroll
        for (int c = 0; c < NCHUNK; c++) m = fmaxf(m, pm[(c*4 + h)*NCRS + row]);
        float lsum = 0.f, asum = 0.f;
#pragma unroll
        for (int c = 0; c < NCHUNK; c++) {
            int pi = (c*4 + h)*NCRS + row;
            float w = __expf(pm[pi] - m);
            lsum += pl[pi] * w;
            asum += pacc[(size_t)pi*64 + d] * w;
        }
        ms[r][t] = asum / lsum;   // t == h*64 + d
    }
    __syncthreads();
    float bv = bm[t];
    float a[4] = {bv, bv, bv, bv};
    for (int c = 0; c < GD; c += 4) {
        float w10 = Wm[(c+0)*GD + t];
        float w11 = Wm[(c+1)*GD + t];
        float w12 = Wm[(c+2)*GD + t];
        float w13 = Wm[(c+3)*GD + t];
        float w20 = Wm[(GD+c+0)*GD + t];
        float w21 = Wm[(GD+c+1)*GD + t];
        float w22 = Wm[(GD+c+2)*GD + t];
        float w23 = Wm[(GD+c+3)*GD + t];
#pragma unroll
        for (int r = 0; r < 4; r++) {
            float4 xv = *(const float4*)&xs[r][c];
            float4 mv = *(const float4*)&ms[r][c];
            a[r] += xv.x*w10 + xv.y*w11 + xv.z*w12 + xv.w*w13
                  + mv.x*w20 + mv.y*w21 + mv.z*w22 + mv.w*w23;
        }
    }
    __syncthreads();               // all ms reads done
#pragma unroll
    for (int r = 0; r < 4; r++) ms[r][t] = xs[r][t] + a[r];   // ms := g2
    __syncthreads();
    float aA[4] = {0.f,0.f,0.f,0.f}, aB[4] = {0.f,0.f,0.f,0.f};
    const float* wA = Ws + t;
    const float* wB = Ws + (size_t)GD*GD + t;
    for (int c = 0; c < GD; c += 4) {
        float wa0 = wA[(size_t)(c+0)*GD], wa1 = wA[(size_t)(c+1)*GD];
        float wa2 = wA[(size_t)(c+2)*GD], wa3 = wA[(size_t)(c+3)*GD];
        float wb0 = wB[(size_t)(c+0)*GD], wb1 = wB[(size_t)(c+1)*GD];
        float wb2 = wB[(size_t)(c+2)*GD], wb3 = wB[(size_t)(c+3)*GD];
#pragma unroll
        for (int r = 0; r < 4; r++) {
            float4 xv = *(const float4*)&ms[r][c];
            aA[r] += xv.x*wa0 + xv.y*wa1 + xv.z*wa2 + xv.w*wa3;
            aB[r] += xv.x*wb0 + xv.y*wb1 + xv.z*wb2 + xv.w*wb3;
        }
    }
#pragma unroll
    for (int r = 0; r < 4; r++) {
        Y[(size_t)(n0+r)*512 + t]      = aA[r];
        Y[(size_t)(n0+r)*512 + GD + t] = aB[r];
    }
}

// =====================================================================
// edge_proj: g3 = edge_max(Y2) (LDS only), feats = g3@Wp + bp,
// then l2norm + score. 4 rows/block, 512 blocks.
// =====================================================================
__global__ __launch_bounds__(256) void edge_proj(
    const float* __restrict__ Y, const int* __restrict__ knn,
    const float* __restrict__ b2, const float* __restrict__ Wp,
    const float* __restrict__ bp, const float* __restrict__ Wsc,
    const float* __restrict__ bsc, float* __restrict__ feats,
    float* __restrict__ fnorm, float* __restrict__ scores)
{
    int t = threadIdx.x, n0 = blockIdx.x * 4;
    __shared__ int ids[4][DGK];
    __shared__ float xg[4][GD];
    __shared__ float pf[4][GD];
    if (t < 4*DGK) {
        int r = t / DGK, j = t - r*DGK;
        int n = n0 + r;
        int base = (n < NSRC) ? 0 : NSRC;
        ids[r][j] = base + knn[n*DGK + j];
    }
    __syncthreads();
#pragma unroll
    for (int r = 0; r < 4; r++) {
        int n = n0 + r;
        float a  = Y[(size_t)n*512 + t];
        float bn = Y[(size_t)n*512 + GD + t];
        float cst = a - bn + b2[t];
        float acc = 0.f;
#pragma unroll
        for (int j = 0; j < DGK; j++) {
            float bj = Y[(size_t)ids[r][j]*512 + GD + t];
            acc = fmaxf(acc, fmaxf(cst + bj, 0.f));
        }
        xg[r][t] = acc;
    }
    __syncthreads();
    float a[4] = {0.f, 0.f, 0.f, 0.f};
    for (int c = 0; c < GD; c += 4) {
        float w0 = Wp[(c+0)*GD + t];
        float w1 = Wp[(c+1)*GD + t];
        float w2 = Wp[(c+2)*GD + t];
        float w3 = Wp[(c+3)*GD + t];
#pragma unroll
        for (int r = 0; r < 4; r++) {
            float4 xv = *(const float4*)&xg[r][c];
            a[r] += xv.x*w0 + xv.y*w1 + xv.z*w2 + xv.w*w3;
        }
    }
    float bv = bp[t];
#pragma unroll
    for (int r = 0; r < 4; r++) {
        float v = a[r] + bv;
        feats[(size_t)(n0+r)*GD + t] = v;
        pf[r][t] = v;
    }
    __syncthreads();
    int lane = t & 63, w = t >> 6;     // wave w handles row w
    int rr = n0 + w;
    float q0 = pf[w][lane], q1 = pf[w][64+lane], q2 = pf[w][128+lane], q3 = pf[w][192+lane];
    float sq = q0*q0 + q1*q1 + q2*q2 + q3*q3;
    float sc = q0*Wsc[lane] + q1*Wsc[64+lane] + q2*Wsc[128+lane] + q3*Wsc[192+lane];
#pragma unroll
    for (int off = 32; off >= 1; off >>= 1) {
        sq += __shfl_xor(sq, off);
        sc += __shfl_xor(sc, off);
    }
    float inv = 1.f / fmaxf(sqrtf(sq), 1e-12f);
    fnorm[(size_t)rr*GD + lane]       = q0*inv;
    fnorm[(size_t)rr*GD + 64 + lane]  = q1*inv;
    fnorm[(size_t)rr*GD + 128 + lane] = q2*inv;
    fnorm[(size_t)rr*GD + 192 + lane] = q3*inv;
    if (lane == 0) scores[rr] = sc + bsc[0];
}

// ip: 4 src rows x 256 tgt cols per block; grid 1024
__global__ __launch_bounds__(256) void ip_kernel(
    const float* __restrict__ fnorm, float* __restrict__ ip)
{
    int t = threadIdx.x;
    int n0 = (blockIdx.x >> 2) * 4;
    int m  = (blockIdx.x & 3) * 256 + t;
    __shared__ float xs[GD][4];
    for (int i = t; i < 4*GD; i += 256) {
        int r = i >> 8, c = i & 255;
        xs[c][r] = fnorm[(size_t)(n0+r)*GD + c];
    }
    __syncthreads();
    const float4* fr = (const float4*)(fnorm + (size_t)(NSRC + m)*GD);
    float a0 = 0.f, a1 = 0.f, a2 = 0.f, a3 = 0.f;
    for (int c4 = 0; c4 < GD/4; c4++) {
        float4 f = fr[c4];
        float4 xa = *(const float4*)&xs[c4*4+0][0];
        float4 xb = *(const float4*)&xs[c4*4+1][0];
        float4 xc = *(const float4*)&xs[c4*4+2][0];
        float4 xd = *(const float4*)&xs[c4*4+3][0];
        a0 += f.x*xa.x + f.y*xb.x + f.z*xc.x + f.w*xd.x;
        a1 += f.x*xa.y + f.y*xb.y + f.z*xc.y + f.w*xd.y;
        a2 += f.x*xa.z + f.y*xb.z + f.z*xc.z + f.w*xd.z;
        a3 += f.x*xa.w + f.y*xb.w + f.z*xc.w + f.w*xd.w;
    }
    ip[(size_t)(n0+0)*NSRC + m] = a0;
    ip[(size_t)(n0+1)*NSRC + m] = a1;
    ip[(size_t)(n0+2)*NSRC + m] = a2;
    ip[(size_t)(n0+3)*NSRC + m] = a3;
}

// =====================================================================
// saliency + dec_coarse fused: block g computes sal[g], then
// decfeat[g][:] = bd + scores[g]*Wd0 + sal[g]*Wd1 + feats[g]·Wd[2:258].
// =====================================================================
__global__ __launch_bounds__(256) void saliency_dec(
    const float* __restrict__ ip, const float* __restrict__ scores,
    const float* __restrict__ epsv, const float* __restrict__ feats,
    const float* __restrict__ Wd, const float* __restrict__ bd,
    float* __restrict__ sal_out, float* __restrict__ decfeat)
{
    int g = blockIdx.x, t = threadIdx.x;
    bool col = (g >= NSRC);
    int n = col ? (g - NSRC) : g;
    const float* so = col ? scores : (scores + NSRC);
    float T = expf(epsv[0]) + 0.03f;
    __shared__ float red[256];
    __shared__ float fr[GD];
    __shared__ float salv;
    for (int c = t; c < GD; c += 256) fr[c] = feats[(size_t)g*GD + c];
    float vals[4];
    float m = -INFINITY;
#pragma unroll
    for (int ii = 0; ii < 4; ii++) {
        int i = t + ii*256;
        float vv = col ? ip[(size_t)i*NSRC + n] : ip[(size_t)n*NSRC + i];
        vv /= T;
        vals[ii] = vv;
        m = fmaxf(m, vv);
    }
    red[t] = m; __syncthreads();
    for (int s = 128; s > 0; s >>= 1) { if (t < s) red[t] = fmaxf(red[t], red[t+s]); __syncthreads(); }
    float mx = red[0]; __syncthreads();
    float se = 0.f, wsum = 0.f;
#pragma unroll
    for (int ii = 0; ii < 4; ii++) {
        int i = t + ii*256;
        float e = expf(vals[ii] - mx);
        se += e; wsum += e * so[i];
    }
    red[t] = se; __syncthreads();
    for (int s = 128; s > 0; s >>= 1) { if (t < s) red[t] += red[t+s]; __syncthreads(); }
    float S = red[0]; __syncthreads();
    red[t] = wsum; __syncthreads();
    for (int s = 128; s > 0; s >>= 1) { if (t < s) red[t] += red[t+s]; __syncthreads(); }
    if (t == 0) {
        float v = red[0] / S;
        sal_out[g] = v;
        salv = v;
    }
    __syncthreads();
    if (t < 40) {
        float acc = 0.f;
        if (t < DECOUT) {
            acc = bd[t] + scores[g]*Wd[t] + salv*Wd[DECOUT + t];
            for (int c = 0; c < GD; c++) acc += fr[c] * Wd[(2 + c)*DECOUT + t];
        }
        decfeat[(size_t)g*40 + t] = acc;
    }
}

// =====================================================================
// decoder — thread per row: acc = decfeat[u] + skip@Wskip (LDS, padded 36)
// =====================================================================
__global__ __launch_bounds__(256) void decoder_kernel(
    const float* __restrict__ decfeat, const float* __restrict__ skip,
    const int* __restrict__ ups, const float* __restrict__ Wd,
    float* __restrict__ outf, float* __restrict__ outso,
    float* __restrict__ outss)
{
    int t = threadIdx.x;
    __shared__ float wsk[C1D*36];   // 18432 B
    for (int i = t; i < C1D*36; i += 256) {
        int cc = i / 36, j = i - cc*36;
        wsk[i] = (j < DECOUT) ? Wd[(size_t)(2 + GD + cc)*DECOUT + j] : 0.f;
    }
    __syncthreads();
    int row = blockIdx.x * 256 + t;
    if (row >= NFINE) return;
    int u = ups[row];
    float4 acc[9];
    const float4* df = (const float4*)(decfeat + (size_t)u*40);
#pragma unroll
    for (int q = 0; q < 9; q++) acc[q] = df[q];
    const float4* sr = (const float4*)(skip + (size_t)row*C1D);
    for (int c4 = 0; c4 < C1D/4; c4++) {
        float4 xv = sr[c4];
        const float* wb = wsk + c4*4*36;
#pragma unroll
        for (int q = 0; q < 9; q++) {
            float4 w0 = *(const float4*)&wb[q*4];
            float4 w1 = *(const float4*)&wb[36 + q*4];
            float4 w2 = *(const float4*)&wb[72 + q*4];
            float4 w3 = *(const float4*)&wb[108 + q*4];
            acc[q].x += xv.x*w0.x + xv.y*w1.x + xv.z*w2.x + xv.w*w3.x;
            acc[q].y += xv.x*w0.y + xv.y*w1.y + xv.z*w2.y + xv.w*w3.y;
            acc[q].z += xv.x*w0.z + xv.y*w1.z + xv.z*w2.z + xv.w*w3.z;
            acc[q].w += xv.x*w0.w + xv.y*w1.w + xv.z*w2.w + xv.w*w3.w;
        }
    }
    float sq = 0.f;
#pragma unroll
    for (int q = 0; q < 8; q++)
        sq += acc[q].x*acc[q].x + acc[q].y*acc[q].y + acc[q].z*acc[q].z + acc[q].w*acc[q].w;
    float inv = 1.f / fmaxf(sqrtf(sq), 1e-12f);
    float4* op = (float4*)(outf + (size_t)row*FINALD);
#pragma unroll
    for (int q = 0; q < 8; q++)
        op[q] = make_float4(acc[q].x*inv, acc[q].y*inv, acc[q].z*inv, acc[q].w*inv);
    float so = 1.f/(1.f + __expf(-acc[8].x));
    so = fminf(fmaxf(so, 0.f), 1.f); if (!(so == so)) so = 0.f;
    float ss = 1.f/(1.f + __expf(-acc[8].y));
    ss = fminf(fmaxf(ss, 0.f), 1.f); if (!(ss == ss)) ss = 0.f;
    outso[row] = so; outss[row] = ss;
}

// =====================================================================
extern "C" void kernel_launch(void* const* d_in, const int* in_sizes, int n_in,
                              void* d_out, int out_size, void* d_ws, size_t ws_size,
                              hipStream_t stream)
{
    const float* points_f     = (const float*)d_in[0];
    const float* points_c     = (const float*)d_in[1];
    const float* features     = (const float*)d_in[2];
    const float* kp_f         = (const float*)d_in[3];
    const float* kp_c         = (const float*)d_in[4];
    const float* W_kp1        = (const float*)d_in[5];
    const float* W_kp2        = (const float*)d_in[6];
    const float* W_bottle     = (const float*)d_in[7];
    const float* b_bottle     = (const float*)d_in[8];
    const float* W_self1      = (const float*)d_in[9];
    const float* b_self1      = (const float*)d_in[10];
    const float* Wq           = (const float*)d_in[11];
    const float* Wk           = (const float*)d_in[12];
    const float* Wv           = (const float*)d_in[13];
    const float* W_cross      = (const float*)d_in[14];
    const float* b_cross      = (const float*)d_in[15];
    const float* W_self2      = (const float*)d_in[16];
    const float* b_self2      = (const float*)d_in[17];
    const float* W_proj       = (const float*)d_in[18];
    const float* b_proj       = (const float*)d_in[19];
    const float* W_score      = (const float*)d_in[20];
    const float* b_score      = (const float*)d_in[21];
    const float* epsilon      = (const float*)d_in[22];
    const float* W_dec        = (const float*)d_in[23];
    const float* b_dec        = (const float*)d_in[24];
    const int*   neighbors_f  = (const int*)d_in[25];
    const int*   pool_idx     = (const int*)d_in[26];
    const int*   upsample_idx = (const int*)d_in[27];

    float* ws = (float*)d_ws;
    size_t o = 0;
    auto alloc = [&](size_t nfl) { float* p = ws + o; o += (nfl + 63) & ~(size_t)63; return p; };
    float* x_f     = alloc((size_t)NFINE * C1D);
    float* g1      = alloc((size_t)NCRS * GD);
    float* qb      = alloc((size_t)NCRS * GD);
    float* kb      = alloc((size_t)NCRS * GD);
    float* vb      = alloc((size_t)NCRS * GD);
    float* scores  = alloc(NCRS);
    float* sal     = alloc(NCRS);
    float* decfeat = alloc((size_t)NCRS * 40);
    int*   knn_b   = (int*)alloc(NCRS * DGK);

    // Union region: phases reuse the same memory (lifetimes are disjoint).
    const size_t NG  = (size_t)NCRS * GD;           // 524288
    const size_t MN  = (size_t)NCRS * C2D;          // 524288
    const size_t PMN = (size_t)NCRS * 4 * NCHUNK;   // 65536
    size_t usz = 4*MN + (size_t)NCRS*KP*C1D;        // 6,029,312 (covers all phases)
    float* U = alloc(usz);
    // encoder: pbuf [hh_gemm -> bottle_self1), hhg [hh_kernel -> hh_gemm)
    float* pbuf = U;
    float* hhg  = U + 4*MN;
    // Y1 written by bottle_self1 (hhg dead), read by edge_qkv
    float* Y1   = U + 4*MN;
    // attention partials [attn -> cross_self2)
    float* pm   = U;
    float* pl   = U + PMN;
    float* pacc = U + 2*PMN;
    // Y2 coexists with partials in cross_self2
    float* Y2   = U + 2*PMN + PMN*64;
    // head phase (partials dead; Y2 read by edge_proj)
    float* feats = U;                               // [0, NG)
    float* fnorm = U + NG;                          // [NG, 2NG)
    float* ip    = U + 2*NG;                        // [2NG, 4NG)

    float* outf  = (float*)d_out;
    float* outso = outf + (size_t)NFINE * FINALD;
    float* outss = outso + NFINE;

    // encoder (+ independent knn fused into the same launch)
    fine_knn<<<FINEB + NCRS, 256, 0, stream>>>(points_f, features, neighbors_f, kp_f,
                                               W_kp1, x_f, points_c, knn_b);
    hh_kernel<<<NCRS, 256, 0, stream>>>(points_c, points_f, x_f, pool_idx, kp_c, hhg);
    hh_gemm<<<(NCRS/GTR)*KC, 256, 0, stream>>>(hhg, W_kp2, pbuf);
    bottle_self1<<<NCRS/4, 256, 0, stream>>>(pbuf, W_bottle, b_bottle, W_self1, Y1);

    // GNN
    edge_qkv<<<NCRS/4, 256, 0, stream>>>(Y1, knn_b, b_self1, Wq, Wk, Wv, g1, qb, kb, vb);
    attn_flash<<<512, 256, 0, stream>>>(qb, kb, vb, pm, pl, pacc);
    cross_self2<<<NCRS/4, 256, 0, stream>>>(g1, pm, pl, pacc, W_cross, b_cross, W_self2, Y2);
    edge_proj<<<NCRS/4, 256, 0, stream>>>(Y2, knn_b, b_self2, W_proj, b_proj,
                                          W_score, b_score, feats, fnorm, scores);

    // head
    ip_kernel<<<NSRC, 256, 0, stream>>>(fnorm, ip);
    saliency_dec<<<NCRS, 256, 0, stream>>>(ip, scores, epsilon, feats, W_dec, b_dec,
                                           sal, decfeat);

    // decoder
    decoder_kernel<<<(NFINE + 255)/256, 256, 0, stream>>>(decfeat, x_f, upsample_idx,
                                                          W_dec, outf, outso, outss);
}